// Round 12
// baseline (179.872 us; speedup 1.0000x reference)
//
#include <hip/hip_runtime.h>
#include <math.h>

// B=4, D=64, N=2304, heads=4, dh=16, scalar=4. Attention output divided by
// bound~2100 => bf16 in the attention branch is ample precision.
// Max-free softmax: logits = -dist/4 with full -0.25*qn_n shift => row max = 0.
// exp2-folding: QFA = bf16(0.5*log2e*q), QFB = bf16(q), QN = -0.25*log2e*|q|^2.
//
// R12: k_attn blocks own 64 q-rows (2 validated 32-row groups) => XF/QA L2
// traffic halves (415MB -> ~210MB). Measured k_attn cost (R11-R10) = 29us.

#define OFF_SC  0
#define OFF_AF  16        // 16384 bf16
#define OFF_QFB 8208      // 589824 bf16
#define OFF_QFA 303120    // 589824 bf16
#define OFF_QN  598032    // 36864 f32
#define OFF_XF  634896    // 589824 bf16
#define OFF_F2  929808    // 2359296 bf16
// total ~8.4 MB of d_ws

#define LOG2E 1.44269504f

typedef __attribute__((ext_vector_type(8))) short bf16x8;
typedef __attribute__((ext_vector_type(16))) float f32x16;
union U4 { uint4 u; bf16x8 b; };

__device__ __forceinline__ unsigned short f2bf(float x) {
    unsigned int u = __float_as_uint(x);
    unsigned int r = u + 0x7fffu + ((u >> 16) & 1u);
    return (unsigned short)(r >> 16);
}
__device__ __forceinline__ float bf2f(unsigned short v) {
    return __uint_as_float((unsigned int)v << 16);
}

// Fused prep: role by blockIdx. 0: bound; 1..64: A; 65..640: q; 641..928: xf.
__global__ __launch_bounds__(256) void k_prep(
    const float* __restrict__ x, const float* __restrict__ Wq,
    const float* __restrict__ bq, const float* __restrict__ Wv,
    const float* __restrict__ Wo, const float* __restrict__ gamma, float* ws)
{
    __shared__ __align__(16) char smem[8192];
    const int bid = blockIdx.x, t = threadIdx.x;

    if (bid == 0) {
        double* red  = (double*)smem;
        double* sums = (double*)(smem + 2048);
        for (int ph = 0; ph < 9; ++ph) {
            double s = 0.0;
            if (ph < 4) {
                const float* W = Wq + ph * 1024;
                for (int i = t; i < 1024; i += 256) { double v = W[i]; s += v * v; }
            } else if (ph < 8) {
                const float* W = Wv + (ph - 4) * 1024;
                for (int i = t; i < 1024; i += 256) { double v = W[i]; s += v * v; }
            } else {
                for (int i = t; i < 4096; i += 256) { double v = Wo[i]; s += v * v; }
            }
            red[t] = s; __syncthreads();
            for (int off = 128; off; off >>= 1) {
                if (t < off) red[t] += red[t + off];
                __syncthreads();
            }
            if (t == 0) sums[ph] = red[0];
            __syncthreads();
        }
        if (t == 0) {
            float z = 2304.0f / 2.7182818284590452f;
            float w = logf(z) - logf(logf(z));
            #pragma unroll 1
            for (int it = 0; it < 30; ++it) {
                float ew = __expf(w);
                w = w - (w * ew - z) / (ew * (w + 1.0f));
            }
            double phi = (double)w;
            double term = sqrt(sums[0]*sums[4] + sums[1]*sums[5] +
                               sums[2]*sums[6] + sums[3]*sums[7]);
            double bound = 6.0 * (4.0 * phi + 1.0) * term * sqrt(sums[8]);
            ws[OFF_SC] = (float)((double)gamma[0] / bound);
        }
    } else if (bid <= 64) {
        float* WlP = (float*)smem;   // [64][17]
        int id = bid - 1, h = id >> 4, dq = id & 15;
        const float* W = Wq + h * 1024;
        for (int i = t; i < 1024; i += 256) WlP[(i >> 4) * 17 + (i & 15)] = W[i];
        __syncthreads();
        int dl = t >> 6, e = t & 63, d = dq * 4 + dl;
        float s = 0.f;
        #pragma unroll
        for (int k = 0; k < 16; ++k) s += WlP[d * 17 + k] * WlP[e * 17 + k];
        int tt = d >> 4, j = d & 7, l = ((d >> 3) & 1) * 32 + (e & 31), ec = e >> 5;
        unsigned short* af = (unsigned short*)(ws + OFF_AF);
        af[(((h * 4 + tt) * 2 + ec) * 64 + l) * 8 + j] = f2bf(0.25f * s);
    } else if (bid <= 640) {
        float* WlT = (float*)smem;           // [64][16]
        float* bl  = (float*)(smem + 4096);  // 16
        float* qnp = (float*)(smem + 4160);  // [4][64]
        int rb = bid - 65, bh = rb / 36, nb = rb % 36;
        int h = bh & 3, b = bh >> 2;
        const float* W = Wq + h * 1024;
        for (int i = t; i < 1024; i += 256) WlT[(i & 63) * 16 + (i >> 6)] = W[i];
        if (t < 16) bl[t] = bq[h * 16 + t];
        __syncthreads();
        int nl = t & 63, kg = t >> 6, n = nb * 64 + nl;
        const float* xb = x + (size_t)b * 147456;
        const float4* wrow = (const float4*)WlT;
        float q0 = bl[kg*4], q1 = bl[kg*4+1], q2 = bl[kg*4+2], q3 = bl[kg*4+3];
        for (int d = 0; d < 64; ++d) {
            float xv = xb[d * 2304 + n];
            float4 wv = wrow[d * 4 + kg];
            q0 = fmaf(wv.x, xv, q0); q1 = fmaf(wv.y, xv, q1);
            q2 = fmaf(wv.z, xv, q2); q3 = fmaf(wv.w, xv, q3);
        }
        qnp[kg * 64 + nl] = q0*q0 + q1*q1 + q2*q2 + q3*q3;
        unsigned pB0 = (unsigned)f2bf(q0) | ((unsigned)f2bf(q1) << 16);
        unsigned pB1 = (unsigned)f2bf(q2) | ((unsigned)f2bf(q3) << 16);
        const float sA = 0.5f * LOG2E;
        unsigned pA0 = (unsigned)f2bf(sA*q0) | ((unsigned)f2bf(sA*q1) << 16);
        unsigned pA1 = (unsigned)f2bf(sA*q2) | ((unsigned)f2bf(sA*q3) << 16);
        size_t base = (size_t)(bh * 72 + (n >> 5)) * 256
                    + (size_t)(((kg >> 1) * 32 + (n & 31)) * 4 + (kg & 1) * 2);
        *(uint2*)((unsigned*)((unsigned short*)(ws + OFF_QFB)) + base) = make_uint2(pB0, pB1);
        *(uint2*)((unsigned*)((unsigned short*)(ws + OFF_QFA)) + base) = make_uint2(pA0, pA1);
        __syncthreads();
        if (t < 64) {
            float qn = qnp[t] + qnp[64 + t] + qnp[128 + t] + qnp[192 + t];
            ws[OFF_QN + bh * 2304 + nb * 64 + t] = -0.25f * LOG2E * qn;
        }
    } else {
        int i = (bid - 641) * 256 + t;
        int l = i & 63, c1 = i >> 6;
        int dc = c1 & 1, c2 = c1 >> 1;
        int T = c2 % 144, b = c2 / 144;
        const float* xb = x + (size_t)b * 147456;
        int col = dc * 32 + (l & 31), mbase = 16 * T + (l >> 5) * 8;
        unsigned int pk[4];
        #pragma unroll
        for (int jj = 0; jj < 4; ++jj) {
            float f0 = xb[(mbase + 2*jj) * 64 + col];
            float f1 = xb[(mbase + 2*jj + 1) * 64 + col];
            pk[jj] = (unsigned int)f2bf(f0) | ((unsigned int)f2bf(f1) << 16);
        }
        ((uint4*)((unsigned short*)(ws + OFF_XF)))[i] = make_uint4(pk[0], pk[1], pk[2], pk[3]);
    }
}

// Streaming (max-free) attention. Block = 4 waves, 64 q-rows (2 groups of 32);
// waves 4-way-split the 72 half-tiles; xv/a0 loaded once per ht, used for
// BOTH q-groups => XF/QA L2 traffic halves vs R10. Grid 576 = 16bh x 36.
__global__ __launch_bounds__(256, 3) void k_attn(float* __restrict__ ws)
{
    __shared__ __align__(16) char smem[40448];
    float* qn_s = (float*)smem;                          // [2304] phase 1
    float (*Ols)[32][68] = (float (*)[32][68])smem;      // [4][32][68] phase 2
    unsigned short (*fls)[80] = (unsigned short (*)[80])(smem + 34816);
    float* Lls = (float*)(smem + 34816 + 5120);          // [4][32]

    const int t = threadIdx.x, w = t >> 6, lane = t & 63;
    // bijective XCD swizzle: 576 blocks = 8 xcd * 72
    const int bid = (blockIdx.x & 7) * 72 + (blockIdx.x >> 3);
    const int bh = bid / 36, rg = bid % 36;              // rg: 64-row group
    const int h = bh & 3;
    const int b = bh >> 2;
    const int hi = lane >> 5, nl = lane & 31, s4 = hi * 4;

    const uint4* QB = (const uint4*)((const unsigned short*)(ws + OFF_QFB)) + (size_t)bh * 4608;
    const uint4* QA = (const uint4*)((const unsigned short*)(ws + OFF_QFA)) + (size_t)bh * 4608;
    const uint4* XF = (const uint4*)((const unsigned short*)(ws + OFF_XF)) + (size_t)b * 18432;
    const float* qn = ws + OFF_QN + bh * 2304;

    // stage qn into LDS (2304 f32 = 576 float4)
    for (int i = t; i < 576; i += 256)
        ((float4*)qn_s)[i] = ((const float4*)qn)[i];

    U4 qb0, qb1;
    qb0.u = QB[(rg * 2 + 0) * 64 + lane];   // rows rg*64 + 0..31 (col n = lane&31)
    qb1.u = QB[(rg * 2 + 1) * 64 + lane];   // rows rg*64 + 32..63
    const float qoffl0 = qn[(rg * 2 + 0) * 32 + nl];
    const float qoffl1 = qn[(rg * 2 + 1) * 32 + nl];

    f32x16 O00, O01, O10, O11;
    #pragma unroll
    for (int i = 0; i < 16; ++i) { O00[i] = 0.f; O01[i] = 0.f; O10[i] = 0.f; O11[i] = 0.f; }
    float lrun0 = 0.f, lrun1 = 0.f;

    __syncthreads();   // qn_s ready

    #pragma unroll 2
    for (int it = 0; it < 18; ++it) {
        const int ht = w + it * 4;          // half-tile: 32 m-rows at m0
        const int m0 = ht * 32;
        U4 xv[4];
        #pragma unroll
        for (int q = 0; q < 4; ++q) xv[q].u = XF[(size_t)(ht * 4 + q) * 64 + lane];
        U4 a0; a0.u = QA[ht * 64 + lane];
        float bc[16];
        #pragma unroll
        for (int g = 0; g < 4; ++g) {
            float4 t4 = *(const float4*)(qn_s + m0 + 8 * g + s4);
            bc[4*g+0] = t4.x; bc[4*g+1] = t4.y; bc[4*g+2] = t4.z; bc[4*g+3] = t4.w;
        }
        // ---- group 0 ----
        {
            f32x16 c0;
            #pragma unroll
            for (int r = 0; r < 16; ++r) c0[r] = bc[r] + qoffl0;
            f32x16 s0 = __builtin_amdgcn_mfma_f32_32x32x16_bf16(a0.b, qb0.b, c0, 0, 0, 0);
            float p[16];
            #pragma unroll
            for (int r = 0; r < 16; ++r)
                asm("v_exp_f32 %0, %1" : "=v"(p[r]) : "v"(s0[r]));
            float la = 0.f, lb = 0.f, lc = 0.f, ld = 0.f;
            #pragma unroll
            for (int r = 0; r < 16; r += 4) {
                la += p[r]; lb += p[r+1]; lc += p[r+2]; ld += p[r+3];
            }
            lrun0 += (la + lb) + (lc + ld);
            unsigned int wd[8], xd[8];
            #pragma unroll
            for (int i = 0; i < 8; ++i)
                asm("v_cvt_pk_bf16_f32 %0, %1, %2"
                    : "=v"(wd[i]) : "v"(p[2*i]), "v"(p[2*i + 1]));
            #pragma unroll
            for (int i = 0; i < 8; ++i) xd[i] = (unsigned int)__shfl_xor((int)wd[i], 32);
            U4 af0, af1;
            af0.u.x = hi ? xd[2] : wd[0];  af0.u.y = hi ? xd[3] : wd[1];
            af0.u.z = hi ? wd[2] : xd[0];  af0.u.w = hi ? wd[3] : xd[1];
            af1.u.x = hi ? xd[6] : wd[4];  af1.u.y = hi ? xd[7] : wd[5];
            af1.u.z = hi ? wd[6] : xd[4];  af1.u.w = hi ? wd[7] : xd[5];
            O00 = __builtin_amdgcn_mfma_f32_32x32x16_bf16(af0.b, xv[0].b, O00, 0, 0, 0);
            O01 = __builtin_amdgcn_mfma_f32_32x32x16_bf16(af0.b, xv[1].b, O01, 0, 0, 0);
            O00 = __builtin_amdgcn_mfma_f32_32x32x16_bf16(af1.b, xv[2].b, O00, 0, 0, 0);
            O01 = __builtin_amdgcn_mfma_f32_32x32x16_bf16(af1.b, xv[3].b, O01, 0, 0, 0);
        }
        // ---- group 1 ----
        {
            f32x16 c1;
            #pragma unroll
            for (int r = 0; r < 16; ++r) c1[r] = bc[r] + qoffl1;
            f32x16 s1 = __builtin_amdgcn_mfma_f32_32x32x16_bf16(a0.b, qb1.b, c1, 0, 0, 0);
            float p[16];
            #pragma unroll
            for (int r = 0; r < 16; ++r)
                asm("v_exp_f32 %0, %1" : "=v"(p[r]) : "v"(s1[r]));
            float la = 0.f, lb = 0.f, lc = 0.f, ld = 0.f;
            #pragma unroll
            for (int r = 0; r < 16; r += 4) {
                la += p[r]; lb += p[r+1]; lc += p[r+2]; ld += p[r+3];
            }
            lrun1 += (la + lb) + (lc + ld);
            unsigned int wd[8], xd[8];
            #pragma unroll
            for (int i = 0; i < 8; ++i)
                asm("v_cvt_pk_bf16_f32 %0, %1, %2"
                    : "=v"(wd[i]) : "v"(p[2*i]), "v"(p[2*i + 1]));
            #pragma unroll
            for (int i = 0; i < 8; ++i) xd[i] = (unsigned int)__shfl_xor((int)wd[i], 32);
            U4 af0, af1;
            af0.u.x = hi ? xd[2] : wd[0];  af0.u.y = hi ? xd[3] : wd[1];
            af0.u.z = hi ? wd[2] : xd[0];  af0.u.w = hi ? wd[3] : xd[1];
            af1.u.x = hi ? xd[6] : wd[4];  af1.u.y = hi ? xd[7] : wd[5];
            af1.u.z = hi ? wd[6] : xd[4];  af1.u.w = hi ? wd[7] : xd[5];
            O10 = __builtin_amdgcn_mfma_f32_32x32x16_bf16(af0.b, xv[0].b, O10, 0, 0, 0);
            O11 = __builtin_amdgcn_mfma_f32_32x32x16_bf16(af0.b, xv[1].b, O11, 0, 0, 0);
            O10 = __builtin_amdgcn_mfma_f32_32x32x16_bf16(af1.b, xv[2].b, O10, 0, 0, 0);
            O11 = __builtin_amdgcn_mfma_f32_32x32x16_bf16(af1.b, xv[3].b, O11, 0, 0, 0);
        }
    }
    __syncthreads();   // all waves done with qn_s before Ols aliases it

    // ---- group 0 epilogue: partials -> combine -> fls ----
    lrun0 += __shfl_xor(lrun0, 32);
    #pragma unroll
    for (int r = 0; r < 16; ++r) {
        int n = (r & 3) + 8 * (r >> 2) + s4;
        Ols[w][n][nl]      = O00[r];
        Ols[w][n][nl + 32] = O01[r];
    }
    if (!hi) Lls[w * 32 + nl] = lrun0;
    __syncthreads();
    {
        int n = t >> 3, d0 = (t & 7) * 8;
        float invL = 1.f / (Lls[n] + Lls[32 + n] + Lls[64 + n] + Lls[96 + n]);
        float f[8];
        #pragma unroll
        for (int j = 0; j < 8; ++j)
            f[j] = (Ols[0][n][d0+j] + Ols[1][n][d0+j] +
                    Ols[2][n][d0+j] + Ols[3][n][d0+j]) * invL;
        unsigned int pk[4];
        #pragma unroll
        for (int i = 0; i < 4; ++i)
            asm("v_cvt_pk_bf16_f32 %0, %1, %2" : "=v"(pk[i]) : "v"(f[2*i]), "v"(f[2*i+1]));
        *(uint4*)((char*)&fls[0][0] + n * 160 + d0 * 2) = make_uint4(pk[0], pk[1], pk[2], pk[3]);
    }
    __syncthreads();

    // ---- group 1 partials (Ols range) + group 0 f@A (fls range, waves 0,1) ----
    lrun1 += __shfl_xor(lrun1, 32);
    #pragma unroll
    for (int r = 0; r < 16; ++r) {
        int n = (r & 3) + 8 * (r >> 2) + s4;
        Ols[w][n][nl]      = O10[r];
        Ols[w][n][nl + 32] = O11[r];
    }
    if (!hi) Lls[w * 32 + nl] = lrun1;
    if (w < 2) {
        const int ec = w;
        const uint4* AFp = (const uint4*)((const unsigned short*)(ws + OFF_AF)) + h * 512;
        f32x16 acc;
        #pragma unroll
        for (int i = 0; i < 16; ++i) acc[i] = 0.f;
        #pragma unroll
        for (int tt = 0; tt < 4; ++tt) {
            U4 a, bb;
            a.u  = *(const uint4*)((const char*)&fls[0][0] + nl * 160 + tt * 32 + hi * 16);
            bb.u = AFp[(tt * 2 + ec) * 64 + lane];
            acc = __builtin_amdgcn_mfma_f32_32x32x16_bf16(a.b, bb.b, acc, 0, 0, 0);
        }
        unsigned short* f2g = (unsigned short*)(ws + OFF_F2) +
                              (size_t)bh * 147456 + (size_t)(rg * 2 + 0) * 32 * 64;
        #pragma unroll
        for (int r = 0; r < 16; ++r)
            f2g[((r & 3) + 8 * (r >> 2) + s4) * 64 + ec * 32 + nl] = f2bf(acc[r]);
    }
    __syncthreads();

    // ---- group 1 combine -> fls ----
    {
        int n = t >> 3, d0 = (t & 7) * 8;
        float invL = 1.f / (Lls[n] + Lls[32 + n] + Lls[64 + n] + Lls[96 + n]);
        float f[8];
        #pragma unroll
        for (int j = 0; j < 8; ++j)
            f[j] = (Ols[0][n][d0+j] + Ols[1][n][d0+j] +
                    Ols[2][n][d0+j] + Ols[3][n][d0+j]) * invL;
        unsigned int pk[4];
        #pragma unroll
        for (int i = 0; i < 4; ++i)
            asm("v_cvt_pk_bf16_f32 %0, %1, %2" : "=v"(pk[i]) : "v"(f[2*i]), "v"(f[2*i+1]));
        *(uint4*)((char*)&fls[0][0] + n * 160 + d0 * 2) = make_uint4(pk[0], pk[1], pk[2], pk[3]);
    }
    __syncthreads();

    // ---- group 1 f@A ----
    if (w < 2) {
        const int ec = w;
        const uint4* AFp = (const uint4*)((const unsigned short*)(ws + OFF_AF)) + h * 512;
        f32x16 acc;
        #pragma unroll
        for (int i = 0; i < 16; ++i) acc[i] = 0.f;
        #pragma unroll
        for (int tt = 0; tt < 4; ++tt) {
            U4 a, bb;
            a.u  = *(const uint4*)((const char*)&fls[0][0] + nl * 160 + tt * 32 + hi * 16);
            bb.u = AFp[(tt * 2 + ec) * 64 + lane];
            acc = __builtin_amdgcn_mfma_f32_32x32x16_bf16(a.b, bb.b, acc, 0, 0, 0);
        }
        unsigned short* f2g = (unsigned short*)(ws + OFF_F2) +
                              (size_t)bh * 147456 + (size_t)(rg * 2 + 1) * 32 * 64;
        #pragma unroll
        for (int r = 0; r < 16; ++r)
            f2g[((r & 3) + 8 * (r >> 2) + s4) * 64 + ec * 32 + nl] = f2bf(acc[r]);
    }
}

// Fused v+out. Block = 16 rows x (4h x 4cq | 16 o-quads). 576 blocks x 256.
__global__ __launch_bounds__(256) void k_post(
    const float* __restrict__ x, const float* __restrict__ Wv,
    const float* __restrict__ bv, const float* __restrict__ Wo,
    const float* __restrict__ bo, const float* __restrict__ ws,
    float* __restrict__ out)
{
    __shared__ float WvL[4096];      // [h][k][d]
    __shared__ float WoT[64 * 68];   // [d][o] pitch 68
    __shared__ float catL[16][68];
    __shared__ float bvL[64], boL[64];
    __shared__ float scs;
    const int bid = blockIdx.x, t = threadIdx.x;
    const int b = bid / 144, n0 = (bid % 144) * 16;
    for (int i = t; i < 4096; i += 256) WvL[i] = Wv[i];
    for (int i = t; i < 4096; i += 256) WoT[(i & 63) * 68 + (i >> 6)] = Wo[i];
    if (t < 64) { bvL[t] = bv[t]; boL[t] = bo[t]; }
    if (t == 0) scs = ws[OFF_SC];
    __syncthreads();

    const int nl = t & 15, q = t >> 4;
    const int n = n0 + nl;
    {
        const int h = q >> 2, cq = q & 3;
        const int k = n / 144;
        const int np = (n % 144) * 16 + cq * 4;
        const unsigned short* f2p = (const unsigned short*)(ws + OFF_F2)
                                  + (size_t)(b * 4 + h) * 147456;
        const float* wv = WvL + h * 1024 + k * 64;
        float bvv = bvL[h * 16 + k];
        float v0 = bvv, v1 = bvv, v2 = bvv, v3 = bvv;
        for (int d = 0; d < 64; ++d) {
            ushort4 f4 = *(const ushort4*)(f2p + d * 2304 + np);
            float wd = wv[d];
            v0 = fmaf(wd, bf2f(f4.x), v0);
            v1 = fmaf(wd, bf2f(f4.y), v1);
            v2 = fmaf(wd, bf2f(f4.z), v2);
            v3 = fmaf(wd, bf2f(f4.w), v3);
        }
        int col = h * 16 + cq * 4;
        catL[nl][col + 0] = v0; catL[nl][col + 1] = v1;
        catL[nl][col + 2] = v2; catL[nl][col + 3] = v3;
    }
    __syncthreads();
    {
        const int oq = q;
        const float4* wo4 = (const float4*)WoT;   // [d][17 float4]
        float a0 = boL[oq*4], a1 = boL[oq*4+1], a2 = boL[oq*4+2], a3 = boL[oq*4+3];
        for (int d = 0; d < 64; ++d) {
            float cv = catL[nl][d];
            float4 w4 = wo4[d * 17 + oq];
            a0 = fmaf(w4.x, cv, a0); a1 = fmaf(w4.y, cv, a1);
            a2 = fmaf(w4.z, cv, a2); a3 = fmaf(w4.w, cv, a3);
        }
        float sc = scs;
        const float* xb = x + (size_t)b * 147456;
        float* ob = out + (size_t)b * 147456;
        int o = oq * 4;
        ob[(o+0) * 2304 + n] = fmaf(sc, a0, xb[(o+0) * 2304 + n]);
        ob[(o+1) * 2304 + n] = fmaf(sc, a1, xb[(o+1) * 2304 + n]);
        ob[(o+2) * 2304 + n] = fmaf(sc, a2, xb[(o+2) * 2304 + n]);
        ob[(o+3) * 2304 + n] = fmaf(sc, a3, xb[(o+3) * 2304 + n]);
    }
}

extern "C" void kernel_launch(void* const* d_in, const int* in_sizes, int n_in,
                              void* d_out, int out_size, void* d_ws, size_t ws_size,
                              hipStream_t stream) {
    const float* x     = (const float*)d_in[0];
    const float* Wq    = (const float*)d_in[1];
    const float* bq    = (const float*)d_in[2];
    const float* Wv    = (const float*)d_in[3];
    const float* bv    = (const float*)d_in[4];
    const float* Wo    = (const float*)d_in[5];
    const float* bo    = (const float*)d_in[6];
    const float* gamma = (const float*)d_in[7];
    float* out = (float*)d_out;
    float* ws  = (float*)d_ws;
    k_prep<<<929, 256, 0, stream>>>(x, Wq, bq, Wv, Wo, gamma, ws);
    k_attn<<<576, 256, 0, stream>>>(ws);
    k_post<<<576, 256, 0, stream>>>(x, Wv, bv, Wo, bo, ws, out);
}

// Round 13
// 129.079 us; speedup vs baseline: 1.3935x; 1.3935x over previous
//
#include <hip/hip_runtime.h>
#include <math.h>

// B=4, D=64, N=2304, heads=4, dh=16, scalar=4. Attention output divided by
// bound~2100 => bf16 in the attention branch is ample precision.
// Max-free softmax: logits = -dist/4 with full -0.25*qn_n shift => row max = 0.
// exp2-folding: QFA = bf16(0.5*log2e*q), QFB = bf16(q), QN = -0.25*log2e*|q|^2.
//
// R13: sigma-trick. QA rows loaded through sigma(row)=swap-bits-2,3 so the
// QK^T output value set per lane-half equals the PV A-frag need:
// af0 = p[0..7], af1 = p[8..15] directly. The per-iteration 8x ds_bpermute
// + 8x select exchange is eliminated (R12's spill-regression reverted).

#define OFF_SC  0
#define OFF_AF  16        // 16384 bf16
#define OFF_QFB 8208      // 589824 bf16
#define OFF_QFA 303120    // 589824 bf16
#define OFF_QN  598032    // 36864 f32
#define OFF_XF  634896    // 589824 bf16
#define OFF_F2  929808    // 2359296 bf16
// total ~8.4 MB of d_ws

#define LOG2E 1.44269504f

typedef __attribute__((ext_vector_type(8))) short bf16x8;
typedef __attribute__((ext_vector_type(16))) float f32x16;
union U4 { uint4 u; bf16x8 b; };

__device__ __forceinline__ unsigned short f2bf(float x) {
    unsigned int u = __float_as_uint(x);
    unsigned int r = u + 0x7fffu + ((u >> 16) & 1u);
    return (unsigned short)(r >> 16);
}
__device__ __forceinline__ float bf2f(unsigned short v) {
    return __uint_as_float((unsigned int)v << 16);
}

// Fused prep: role by blockIdx. 0: bound; 1..64: A; 65..640: q; 641..928: xf.
// Byte-identical to R10 (validated).
__global__ __launch_bounds__(256) void k_prep(
    const float* __restrict__ x, const float* __restrict__ Wq,
    const float* __restrict__ bq, const float* __restrict__ Wv,
    const float* __restrict__ Wo, const float* __restrict__ gamma, float* ws)
{
    __shared__ __align__(16) char smem[8192];
    const int bid = blockIdx.x, t = threadIdx.x;

    if (bid == 0) {
        double* red  = (double*)smem;
        double* sums = (double*)(smem + 2048);
        for (int ph = 0; ph < 9; ++ph) {
            double s = 0.0;
            if (ph < 4) {
                const float* W = Wq + ph * 1024;
                for (int i = t; i < 1024; i += 256) { double v = W[i]; s += v * v; }
            } else if (ph < 8) {
                const float* W = Wv + (ph - 4) * 1024;
                for (int i = t; i < 1024; i += 256) { double v = W[i]; s += v * v; }
            } else {
                for (int i = t; i < 4096; i += 256) { double v = Wo[i]; s += v * v; }
            }
            red[t] = s; __syncthreads();
            for (int off = 128; off; off >>= 1) {
                if (t < off) red[t] += red[t + off];
                __syncthreads();
            }
            if (t == 0) sums[ph] = red[0];
            __syncthreads();
        }
        if (t == 0) {
            float z = 2304.0f / 2.7182818284590452f;
            float w = logf(z) - logf(logf(z));
            #pragma unroll 1
            for (int it = 0; it < 30; ++it) {
                float ew = __expf(w);
                w = w - (w * ew - z) / (ew * (w + 1.0f));
            }
            double phi = (double)w;
            double term = sqrt(sums[0]*sums[4] + sums[1]*sums[5] +
                               sums[2]*sums[6] + sums[3]*sums[7]);
            double bound = 6.0 * (4.0 * phi + 1.0) * term * sqrt(sums[8]);
            ws[OFF_SC] = (float)((double)gamma[0] / bound);
        }
    } else if (bid <= 64) {
        float* WlP = (float*)smem;   // [64][17]
        int id = bid - 1, h = id >> 4, dq = id & 15;
        const float* W = Wq + h * 1024;
        for (int i = t; i < 1024; i += 256) WlP[(i >> 4) * 17 + (i & 15)] = W[i];
        __syncthreads();
        int dl = t >> 6, e = t & 63, d = dq * 4 + dl;
        float s = 0.f;
        #pragma unroll
        for (int k = 0; k < 16; ++k) s += WlP[d * 17 + k] * WlP[e * 17 + k];
        int tt = d >> 4, j = d & 7, l = ((d >> 3) & 1) * 32 + (e & 31), ec = e >> 5;
        unsigned short* af = (unsigned short*)(ws + OFF_AF);
        af[(((h * 4 + tt) * 2 + ec) * 64 + l) * 8 + j] = f2bf(0.25f * s);
    } else if (bid <= 640) {
        float* WlT = (float*)smem;           // [64][16]
        float* bl  = (float*)(smem + 4096);  // 16
        float* qnp = (float*)(smem + 4160);  // [4][64]
        int rb = bid - 65, bh = rb / 36, nb = rb % 36;
        int h = bh & 3, b = bh >> 2;
        const float* W = Wq + h * 1024;
        for (int i = t; i < 1024; i += 256) WlT[(i & 63) * 16 + (i >> 6)] = W[i];
        if (t < 16) bl[t] = bq[h * 16 + t];
        __syncthreads();
        int nl = t & 63, kg = t >> 6, n = nb * 64 + nl;
        const float* xb = x + (size_t)b * 147456;
        const float4* wrow = (const float4*)WlT;
        float q0 = bl[kg*4], q1 = bl[kg*4+1], q2 = bl[kg*4+2], q3 = bl[kg*4+3];
        for (int d = 0; d < 64; ++d) {
            float xv = xb[d * 2304 + n];
            float4 wv = wrow[d * 4 + kg];
            q0 = fmaf(wv.x, xv, q0); q1 = fmaf(wv.y, xv, q1);
            q2 = fmaf(wv.z, xv, q2); q3 = fmaf(wv.w, xv, q3);
        }
        qnp[kg * 64 + nl] = q0*q0 + q1*q1 + q2*q2 + q3*q3;
        unsigned pB0 = (unsigned)f2bf(q0) | ((unsigned)f2bf(q1) << 16);
        unsigned pB1 = (unsigned)f2bf(q2) | ((unsigned)f2bf(q3) << 16);
        const float sA = 0.5f * LOG2E;
        unsigned pA0 = (unsigned)f2bf(sA*q0) | ((unsigned)f2bf(sA*q1) << 16);
        unsigned pA1 = (unsigned)f2bf(sA*q2) | ((unsigned)f2bf(sA*q3) << 16);
        size_t base = (size_t)(bh * 72 + (n >> 5)) * 256
                    + (size_t)(((kg >> 1) * 32 + (n & 31)) * 4 + (kg & 1) * 2);
        *(uint2*)((unsigned*)((unsigned short*)(ws + OFF_QFB)) + base) = make_uint2(pB0, pB1);
        *(uint2*)((unsigned*)((unsigned short*)(ws + OFF_QFA)) + base) = make_uint2(pA0, pA1);
        __syncthreads();
        if (t < 64) {
            float qn = qnp[t] + qnp[64 + t] + qnp[128 + t] + qnp[192 + t];
            ws[OFF_QN + bh * 2304 + nb * 64 + t] = -0.25f * LOG2E * qn;
        }
    } else {
        int i = (bid - 641) * 256 + t;
        int l = i & 63, c1 = i >> 6;
        int dc = c1 & 1, c2 = c1 >> 1;
        int T = c2 % 144, b = c2 / 144;
        const float* xb = x + (size_t)b * 147456;
        int col = dc * 32 + (l & 31), mbase = 16 * T + (l >> 5) * 8;
        unsigned int pk[4];
        #pragma unroll
        for (int jj = 0; jj < 4; ++jj) {
            float f0 = xb[(mbase + 2*jj) * 64 + col];
            float f1 = xb[(mbase + 2*jj + 1) * 64 + col];
            pk[jj] = (unsigned int)f2bf(f0) | ((unsigned int)f2bf(f1) << 16);
        }
        ((uint4*)((unsigned short*)(ws + OFF_XF)))[i] = make_uint4(pk[0], pk[1], pk[2], pk[3]);
    }
}

// Streaming (max-free) attention. Block = 4 waves = 32 q-rows; 4-way m-split
// over 72 half-tiles. Sigma-permuted QA rows => exchange-free P->A-frag.
__global__ __launch_bounds__(256, 4) void k_attn(float* __restrict__ ws)
{
    __shared__ __align__(16) char smem[40448];
    float* qn_s = (float*)smem;                          // [2304] phase 1
    float (*Ols)[32][68] = (float (*)[32][68])smem;      // [4][32][68] phase 2
    unsigned short (*fls)[80] = (unsigned short (*)[80])(smem + 34816);
    float* Lls = (float*)(smem + 34816 + 5120);          // [4][32]

    const int t = threadIdx.x, w = t >> 6, lane = t & 63;
    // bijective XCD swizzle: 1152 blocks = 8 xcd * 144
    const int bid = (blockIdx.x & 7) * 144 + (blockIdx.x >> 3);
    const int bh = bid / 72, rc = bid % 72;
    const int h = bh & 3;
    const int b = bh >> 2;
    const int hi = lane >> 5, nl = lane & 31, s4 = hi * 4;
    // sigma: swap bits 2,3 (involution). sigma-row load of QA makes the QK
    // output per-lane value set equal the PV A-frag need.
    const int snl = (nl & ~12) | ((nl & 4) << 1) | ((nl & 8) >> 1);

    const uint4* QB = (const uint4*)((const unsigned short*)(ws + OFF_QFB)) + (size_t)bh * 4608;
    const uint4* QA = (const uint4*)((const unsigned short*)(ws + OFF_QFA)) + (size_t)bh * 4608;
    const uint4* XF = (const uint4*)((const unsigned short*)(ws + OFF_XF)) + (size_t)b * 18432;
    const float* qn = ws + OFF_QN + bh * 2304;

    // stage qn into LDS (2304 f32 = 576 float4)
    for (int i = t; i < 576; i += 256)
        ((float4*)qn_s)[i] = ((const float4*)qn)[i];

    U4 qb; qb.u = QB[rc * 64 + lane];
    const float qoffl = qn[rc * 32 + nl];

    f32x16 O0, O1;
    #pragma unroll
    for (int i = 0; i < 16; ++i) { O0[i] = 0.f; O1[i] = 0.f; }
    float lrun = 0.f;

    __syncthreads();   // qn_s ready

    #pragma unroll 2
    for (int it = 0; it < 18; ++it) {
        const int ht = w + it * 4;          // half-tile: 32 m-rows at m0
        const int m0 = ht * 32;
        U4 xv[4];
        #pragma unroll
        for (int q = 0; q < 4; ++q) xv[q].u = XF[(size_t)(ht * 4 + q) * 64 + lane];
        U4 a0; a0.u = QA[ht * 64 + (lane & 32) + snl];   // sigma-row load
        f32x16 c0;
        #pragma unroll
        for (int g = 0; g < 4; ++g) {
            // C row for reg r=4g+j is sigma(8g+4hi+j) = 16(g>>1)+8hi+4(g&1)+j
            float4 t4 = *(const float4*)(qn_s + m0 + 16 * (g >> 1) + 8 * hi + 4 * (g & 1));
            c0[4*g+0] = t4.x + qoffl; c0[4*g+1] = t4.y + qoffl;
            c0[4*g+2] = t4.z + qoffl; c0[4*g+3] = t4.w + qoffl;
        }
        f32x16 s0 = __builtin_amdgcn_mfma_f32_32x32x16_bf16(a0.b, qb.b, c0, 0, 0, 0);
        float p[16];
        #pragma unroll
        for (int r = 0; r < 16; ++r)
            asm("v_exp_f32 %0, %1" : "=v"(p[r]) : "v"(s0[r]));
        float la = 0.f, lb = 0.f, lc = 0.f, ld = 0.f;
        #pragma unroll
        for (int r = 0; r < 16; r += 4) {
            la += p[r]; lb += p[r+1]; lc += p[r+2]; ld += p[r+3];
        }
        lrun += (la + lb) + (lc + ld);
        // P -> bf16 A-frags: with sigma, af0 = p[0..7], af1 = p[8..15]. No exchange.
        unsigned int wd[8];
        #pragma unroll
        for (int i = 0; i < 8; ++i)
            asm("v_cvt_pk_bf16_f32 %0, %1, %2"
                : "=v"(wd[i]) : "v"(p[2*i]), "v"(p[2*i + 1]));
        U4 af0, af1;
        af0.u.x = wd[0]; af0.u.y = wd[1]; af0.u.z = wd[2]; af0.u.w = wd[3];
        af1.u.x = wd[4]; af1.u.y = wd[5]; af1.u.z = wd[6]; af1.u.w = wd[7];
        O0 = __builtin_amdgcn_mfma_f32_32x32x16_bf16(af0.b, xv[0].b, O0, 0, 0, 0);
        O1 = __builtin_amdgcn_mfma_f32_32x32x16_bf16(af0.b, xv[1].b, O1, 0, 0, 0);
        O0 = __builtin_amdgcn_mfma_f32_32x32x16_bf16(af1.b, xv[2].b, O0, 0, 0, 0);
        O1 = __builtin_amdgcn_mfma_f32_32x32x16_bf16(af1.b, xv[3].b, O1, 0, 0, 0);
    }
    __syncthreads();   // all waves done with qn_s before Ols aliases it

    // partial state -> LDS
    lrun += __shfl_xor(lrun, 32);
    #pragma unroll
    for (int r = 0; r < 16; ++r) {
        int n = (r & 3) + 8 * (r >> 2) + s4;
        Ols[w][n][nl]      = O0[r];
        Ols[w][n][nl + 32] = O1[r];
    }
    if (!hi) Lls[w * 32 + nl] = lrun;
    __syncthreads();

    // combine 4 partials, normalize, write f as bf16 tile
    {
        int n = t >> 3, d0 = (t & 7) * 8;
        float invL = 1.f / (Lls[n] + Lls[32 + n] + Lls[64 + n] + Lls[96 + n]);
        float f[8];
        #pragma unroll
        for (int j = 0; j < 8; ++j)
            f[j] = (Ols[0][n][d0+j] + Ols[1][n][d0+j] +
                    Ols[2][n][d0+j] + Ols[3][n][d0+j]) * invL;
        unsigned int pk[4];
        #pragma unroll
        for (int i = 0; i < 4; ++i)
            asm("v_cvt_pk_bf16_f32 %0, %1, %2" : "=v"(pk[i]) : "v"(f[2*i]), "v"(f[2*i+1]));
        *(uint4*)((char*)&fls[0][0] + n * 160 + d0 * 2) = make_uint4(pk[0], pk[1], pk[2], pk[3]);
    }
    __syncthreads();

    // f2 = f @ A : waves 0,1 handle e-columns ec*32..+31; store bf16
    if (w < 2) {
        const int ec = w;
        const uint4* AFp = (const uint4*)((const unsigned short*)(ws + OFF_AF)) + h * 512;
        f32x16 acc;
        #pragma unroll
        for (int i = 0; i < 16; ++i) acc[i] = 0.f;
        #pragma unroll
        for (int tt = 0; tt < 4; ++tt) {
            U4 a, bb;
            a.u  = *(const uint4*)((const char*)&fls[0][0] + nl * 160 + tt * 32 + hi * 16);
            bb.u = AFp[(tt * 2 + ec) * 64 + lane];
            acc = __builtin_amdgcn_mfma_f32_32x32x16_bf16(a.b, bb.b, acc, 0, 0, 0);
        }
        unsigned short* f2g = (unsigned short*)(ws + OFF_F2) +
                              (size_t)bh * 147456 + (size_t)rc * 32 * 64;
        #pragma unroll
        for (int r = 0; r < 16; ++r)
            f2g[((r & 3) + 8 * (r >> 2) + s4) * 64 + ec * 32 + nl] = f2bf(acc[r]);
    }
}

// Fused v+out. Block = 16 rows x (4h x 4cq | 16 o-quads). 576 blocks x 256.
// Byte-identical to R10 (validated).
__global__ __launch_bounds__(256) void k_post(
    const float* __restrict__ x, const float* __restrict__ Wv,
    const float* __restrict__ bv, const float* __restrict__ Wo,
    const float* __restrict__ bo, const float* __restrict__ ws,
    float* __restrict__ out)
{
    __shared__ float WvL[4096];      // [h][k][d]
    __shared__ float WoT[64 * 68];   // [d][o] pitch 68
    __shared__ float catL[16][68];
    __shared__ float bvL[64], boL[64];
    __shared__ float scs;
    const int bid = blockIdx.x, t = threadIdx.x;
    const int b = bid / 144, n0 = (bid % 144) * 16;
    for (int i = t; i < 4096; i += 256) WvL[i] = Wv[i];
    for (int i = t; i < 4096; i += 256) WoT[(i & 63) * 68 + (i >> 6)] = Wo[i];
    if (t < 64) { bvL[t] = bv[t]; boL[t] = bo[t]; }
    if (t == 0) scs = ws[OFF_SC];
    __syncthreads();

    const int nl = t & 15, q = t >> 4;
    const int n = n0 + nl;
    {
        const int h = q >> 2, cq = q & 3;
        const int k = n / 144;
        const int np = (n % 144) * 16 + cq * 4;
        const unsigned short* f2p = (const unsigned short*)(ws + OFF_F2)
                                  + (size_t)(b * 4 + h) * 147456;
        const float* wv = WvL + h * 1024 + k * 64;
        float bvv = bvL[h * 16 + k];
        float v0 = bvv, v1 = bvv, v2 = bvv, v3 = bvv;
        for (int d = 0; d < 64; ++d) {
            ushort4 f4 = *(const ushort4*)(f2p + d * 2304 + np);
            float wd = wv[d];
            v0 = fmaf(wd, bf2f(f4.x), v0);
            v1 = fmaf(wd, bf2f(f4.y), v1);
            v2 = fmaf(wd, bf2f(f4.z), v2);
            v3 = fmaf(wd, bf2f(f4.w), v3);
        }
        int col = h * 16 + cq * 4;
        catL[nl][col + 0] = v0; catL[nl][col + 1] = v1;
        catL[nl][col + 2] = v2; catL[nl][col + 3] = v3;
    }
    __syncthreads();
    {
        const int oq = q;
        const float4* wo4 = (const float4*)WoT;   // [d][17 float4]
        float a0 = boL[oq*4], a1 = boL[oq*4+1], a2 = boL[oq*4+2], a3 = boL[oq*4+3];
        for (int d = 0; d < 64; ++d) {
            float cv = catL[nl][d];
            float4 w4 = wo4[d * 17 + oq];
            a0 = fmaf(w4.x, cv, a0); a1 = fmaf(w4.y, cv, a1);
            a2 = fmaf(w4.z, cv, a2); a3 = fmaf(w4.w, cv, a3);
        }
        float sc = scs;
        const float* xb = x + (size_t)b * 147456;
        float* ob = out + (size_t)b * 147456;
        int o = oq * 4;
        ob[(o+0) * 2304 + n] = fmaf(sc, a0, xb[(o+0) * 2304 + n]);
        ob[(o+1) * 2304 + n] = fmaf(sc, a1, xb[(o+1) * 2304 + n]);
        ob[(o+2) * 2304 + n] = fmaf(sc, a2, xb[(o+2) * 2304 + n]);
        ob[(o+3) * 2304 + n] = fmaf(sc, a3, xb[(o+3) * 2304 + n]);
    }
}

extern "C" void kernel_launch(void* const* d_in, const int* in_sizes, int n_in,
                              void* d_out, int out_size, void* d_ws, size_t ws_size,
                              hipStream_t stream) {
    const float* x     = (const float*)d_in[0];
    const float* Wq    = (const float*)d_in[1];
    const float* bq    = (const float*)d_in[2];
    const float* Wv    = (const float*)d_in[3];
    const float* bv    = (const float*)d_in[4];
    const float* Wo    = (const float*)d_in[5];
    const float* bo    = (const float*)d_in[6];
    const float* gamma = (const float*)d_in[7];
    float* out = (float*)d_out;
    float* ws  = (float*)d_ws;
    k_prep<<<929,  256, 0, stream>>>(x, Wq, bq, Wv, Wo, gamma, ws);
    k_attn<<<1152, 256, 0, stream>>>(ws);
    k_post<<<576,  256, 0, stream>>>(x, Wv, bv, Wo, bo, ws, out);
}